// Round 1
// baseline (1522.690 us; speedup 1.0000x reference)
//
#include <hip/hip_runtime.h>
#include <hip/hip_bf16.h>

// Problem constants (from reference)
#define TT 4096
#define HH 2048
#define CI 2816        // I
#define EE 8
#define KK 2
#define TKN (TT * KK)  // 8192 assignments
#define TM 128         // token-tile (M)
#define BK 64          // K-tile
#define MAX_MT (TKN / TM + EE)   // 72 worst-case m-tiles (per-expert ceil rounding)
#define ROWS_PAD (MAX_MT * TM)   // 9216 padded rows
#define LDA 72                   // LDS row stride in bf16 (64 + 8 pad, keeps 16B align)

typedef short short8 __attribute__((ext_vector_type(8)));
typedef float floatx4 __attribute__((ext_vector_type(4)));

__device__ __forceinline__ unsigned short f2bf(float f) {
  // round-to-nearest (half-up) fp32 -> bf16; inputs are finite
  unsigned u = __float_as_uint(f);
  return (unsigned short)((u + 0x8000u) >> 16);
}

__device__ __forceinline__ void cvt_store8(unsigned short* dst, float4 a, float4 b) {
  short8 v;
  v[0] = (short)f2bf(a.x); v[1] = (short)f2bf(a.y);
  v[2] = (short)f2bf(a.z); v[3] = (short)f2bf(a.w);
  v[4] = (short)f2bf(b.x); v[5] = (short)f2bf(b.y);
  v[6] = (short)f2bf(b.z); v[7] = (short)f2bf(b.w);
  *(short8*)dst = v;
}

// ---------------------------------------------------------------------------
// Kernel 1: bucket tokens by expert into padded TM-row regions.
// hdr[0] = ntiles, hdr[1+mt] = expert id of tile mt.
// tok[row], wt[row] for each padded row (padding: tok=0, wt=0).
// ---------------------------------------------------------------------------
__global__ void bucket_kernel(const int* __restrict__ ids, const float* __restrict__ tw,
                              int* __restrict__ hdr, int* __restrict__ tok,
                              float* __restrict__ wt) {
  __shared__ int cnt[EE];
  __shared__ int cur[EE];
  int tid = threadIdx.x;
  if (tid < EE) cnt[tid] = 0;
  __syncthreads();
  for (int p = tid; p < TKN; p += 256) atomicAdd(&cnt[ids[p]], 1);
  // zero the padded row arrays (ws is poisoned each call)
  for (int r = tid; r < ROWS_PAD; r += 256) { tok[r] = 0; wt[r] = 0.f; }
  __syncthreads();
  if (tid == 0) {
    int rb = 0, tb = 0;
    for (int e = 0; e < EE; e++) {
      cur[e] = rb;
      int nt = (cnt[e] + TM - 1) / TM;
      for (int j = 0; j < nt; j++) hdr[1 + tb + j] = e;
      rb += nt * TM;
      tb += nt;
    }
    for (int m = tb; m < MAX_MT; m++) hdr[1 + m] = 0;
    hdr[0] = tb;
  }
  __syncthreads();
  for (int p = tid; p < TKN; p += 256) {
    int e = ids[p];
    int slot = atomicAdd(&cur[e], 1);
    tok[slot] = p / KK;
    wt[slot] = tw[p];
  }
}

// ---------------------------------------------------------------------------
// Kernel 2 (GEMM1): act[row, i] = silu(x_row . w_gate[e,i]) * (x_row . w_up[e,i])
// Block: one (m-tile, 64-wide act column tile). B-tile = 64 gate rows + 64 up rows.
// ---------------------------------------------------------------------------
__global__ __launch_bounds__(256, 2)
void gemm1_kernel(const float* __restrict__ x, const float* __restrict__ w13,
                  const int* __restrict__ hdr, const int* __restrict__ tok,
                  unsigned short* __restrict__ act) {
  const int mt = blockIdx.x;
  if (mt >= hdr[0]) return;
  const int e = hdr[1 + mt];
  const int bn = blockIdx.y;          // 0..43, act cols [bn*64, bn*64+64)
  const int row_base = mt * TM;
  const int tid = threadIdx.x;

  __shared__ __align__(16) unsigned short As[TM][LDA];
  __shared__ __align__(16) unsigned short Bs[TM][LDA];
  __shared__ int tok_s[TM];

  if (tid < TM) tok_s[tid] = tok[row_base + tid];
  __syncthreads();

  // Each thread stages 4 octets (8 floats) of A and 4 of B per K-step.
  const float* apA[4];
  const float* apB[4];
  unsigned short* ldA[4];
  unsigned short* ldB[4];
#pragma unroll
  for (int i = 0; i < 4; i++) {
    int u = i * 256 + tid;     // octet id 0..1023
    int r = u >> 3;            // tile row 0..127
    int ko = (u & 7) * 8;      // k offset
    apA[i] = x + (size_t)tok_s[r] * HH + ko;
    int wrow = (r < 64) ? (bn * 64 + r) : (CI + bn * 64 + (r - 64));
    apB[i] = w13 + ((size_t)e * (2 * CI) + wrow) * HH + ko;
    ldA[i] = &As[r][ko];
    ldB[i] = &Bs[r][ko];
  }

  floatx4 acc[2][8];
#pragma unroll
  for (int mi = 0; mi < 2; mi++)
#pragma unroll
    for (int ni = 0; ni < 8; ni++) acc[mi][ni] = (floatx4){0.f, 0.f, 0.f, 0.f};

  const int lane = tid & 63;
  const int wave = tid >> 6;
  const int lrow = lane & 15;
  const int quad = lane >> 4;
  const int m0 = wave * 32;

  for (int k0 = 0; k0 < HH; k0 += BK) {
    __syncthreads();
#pragma unroll
    for (int i = 0; i < 4; i++) {
      float4 a0 = *(const float4*)(apA[i] + k0);
      float4 a1 = *(const float4*)(apA[i] + k0 + 4);
      float4 b0 = *(const float4*)(apB[i] + k0);
      float4 b1 = *(const float4*)(apB[i] + k0 + 4);
      cvt_store8(ldA[i], a0, a1);
      cvt_store8(ldB[i], b0, b1);
    }
    __syncthreads();
#pragma unroll
    for (int kh = 0; kh < 2; kh++) {
      short8 af0 = *(const short8*)&As[m0 + lrow][kh * 32 + quad * 8];
      short8 af1 = *(const short8*)&As[m0 + 16 + lrow][kh * 32 + quad * 8];
#pragma unroll
      for (int ni = 0; ni < 8; ni++) {
        short8 bf = *(const short8*)&Bs[ni * 16 + lrow][kh * 32 + quad * 8];
        acc[0][ni] = __builtin_amdgcn_mfma_f32_16x16x32_bf16(af0, bf, acc[0][ni], 0, 0, 0);
        acc[1][ni] = __builtin_amdgcn_mfma_f32_16x16x32_bf16(af1, bf, acc[1][ni], 0, 0, 0);
      }
    }
  }

  // Epilogue: cols 0..63 of C are gate, 64..127 are up (same frag mapping) -> silu*up
  const int col0 = bn * 64;
#pragma unroll
  for (int mi = 0; mi < 2; mi++) {
#pragma unroll
    for (int ni = 0; ni < 4; ni++) {
#pragma unroll
      for (int r = 0; r < 4; r++) {
        float g = acc[mi][ni][r];
        float uu = acc[mi][ni + 4][r];
        float s = g / (1.f + __expf(-g));   // silu(g)
        int row = row_base + m0 + mi * 16 + quad * 4 + r;
        int col = col0 + ni * 16 + lrow;
        act[(size_t)row * CI + col] = f2bf(s * uu);
      }
    }
  }
}

// ---------------------------------------------------------------------------
// Kernel 3 (GEMM2): y[row, h] = act_row . w2[e, h, :]; out[tok[row], h] += wt[row]*y
// ---------------------------------------------------------------------------
__global__ __launch_bounds__(256, 2)
void gemm2_kernel(const unsigned short* __restrict__ act, const float* __restrict__ w2,
                  const int* __restrict__ hdr, const int* __restrict__ tok,
                  const float* __restrict__ wt, float* __restrict__ out) {
  const int mt = blockIdx.x;
  if (mt >= hdr[0]) return;
  const int e = hdr[1 + mt];
  const int h0 = blockIdx.y * TM;     // 128 output cols
  const int row_base = mt * TM;
  const int tid = threadIdx.x;

  __shared__ __align__(16) unsigned short As[TM][LDA];
  __shared__ __align__(16) unsigned short Bs[TM][LDA];
  __shared__ int tok_s[TM];
  __shared__ float wt_s[TM];

  if (tid < TM) {
    tok_s[tid] = tok[row_base + tid];
    wt_s[tid] = wt[row_base + tid];
  }

  const unsigned short* apA[4];
  const float* apB[4];
  unsigned short* ldA[4];
  unsigned short* ldB[4];
#pragma unroll
  for (int i = 0; i < 4; i++) {
    int u = i * 256 + tid;
    int r = u >> 3;
    int ko = (u & 7) * 8;
    apA[i] = act + (size_t)(row_base + r) * CI + ko;
    apB[i] = w2 + ((size_t)e * HH + h0 + r) * CI + ko;
    ldA[i] = &As[r][ko];
    ldB[i] = &Bs[r][ko];
  }

  floatx4 acc[2][8];
#pragma unroll
  for (int mi = 0; mi < 2; mi++)
#pragma unroll
    for (int ni = 0; ni < 8; ni++) acc[mi][ni] = (floatx4){0.f, 0.f, 0.f, 0.f};

  const int lane = tid & 63;
  const int wave = tid >> 6;
  const int lrow = lane & 15;
  const int quad = lane >> 4;
  const int m0 = wave * 32;

  for (int k0 = 0; k0 < CI; k0 += BK) {
    __syncthreads();
#pragma unroll
    for (int i = 0; i < 4; i++) {
      short8 av = *(const short8*)(apA[i] + k0);   // A already bf16
      float4 b0 = *(const float4*)(apB[i] + k0);
      float4 b1 = *(const float4*)(apB[i] + k0 + 4);
      *(short8*)ldA[i] = av;
      cvt_store8(ldB[i], b0, b1);
    }
    __syncthreads();
#pragma unroll
    for (int kh = 0; kh < 2; kh++) {
      short8 af0 = *(const short8*)&As[m0 + lrow][kh * 32 + quad * 8];
      short8 af1 = *(const short8*)&As[m0 + 16 + lrow][kh * 32 + quad * 8];
#pragma unroll
      for (int ni = 0; ni < 8; ni++) {
        short8 bf = *(const short8*)&Bs[ni * 16 + lrow][kh * 32 + quad * 8];
        acc[0][ni] = __builtin_amdgcn_mfma_f32_16x16x32_bf16(af0, bf, acc[0][ni], 0, 0, 0);
        acc[1][ni] = __builtin_amdgcn_mfma_f32_16x16x32_bf16(af1, bf, acc[1][ni], 0, 0, 0);
      }
    }
  }

#pragma unroll
  for (int mi = 0; mi < 2; mi++) {
#pragma unroll
    for (int ni = 0; ni < 8; ni++) {
#pragma unroll
      for (int r = 0; r < 4; r++) {
        int lr = m0 + mi * 16 + quad * 4 + r;
        float w = wt_s[lr];
        if (w != 0.f) {
          float v = acc[mi][ni][r] * w;
          atomicAdd(out + (size_t)tok_s[lr] * HH + h0 + ni * 16 + lrow, v);
        }
      }
    }
  }
}

extern "C" void kernel_launch(void* const* d_in, const int* in_sizes, int n_in,
                              void* d_out, int out_size, void* d_ws, size_t ws_size,
                              hipStream_t stream) {
  const float* x   = (const float*)d_in[0];
  const float* w13 = (const float*)d_in[1];
  const float* w2  = (const float*)d_in[2];
  const float* tw  = (const float*)d_in[3];
  const int*   ids = (const int*)d_in[4];
  float* out = (float*)d_out;

  // workspace layout
  char* ws = (char*)d_ws;
  int* hdr = (int*)ws;                                   // (1 + MAX_MT) ints
  int* tok = (int*)(ws + 512);                           // ROWS_PAD ints
  float* wt = (float*)(ws + 512 + ROWS_PAD * 4);         // ROWS_PAD floats
  unsigned short* act = (unsigned short*)(ws + 512 + ROWS_PAD * 8);  // ROWS_PAD * CI bf16

  hipMemsetAsync(d_out, 0, (size_t)out_size * sizeof(float), stream);
  bucket_kernel<<<1, 256, 0, stream>>>(ids, tw, hdr, tok, wt);
  gemm1_kernel<<<dim3(MAX_MT, CI / 64), 256, 0, stream>>>(x, w13, hdr, tok, act);
  gemm2_kernel<<<dim3(MAX_MT, HH / TM), 256, 0, stream>>>(act, w2, hdr, tok, wt, out);
}

// Round 2
// 1188.533 us; speedup vs baseline: 1.2812x; 1.2812x over previous
//
#include <hip/hip_runtime.h>
#include <hip/hip_bf16.h>

// Problem constants
#define TT 4096
#define HH 2048
#define CI 2816        // I
#define EE 8
#define KK 2
#define TKN (TT * KK)  // 8192 assignments
#define TM 128         // M tile
#define BK 64          // K tile
#define MAX_MT (TKN / TM + EE)   // 72 worst-case m-tiles
#define ROWS_PAD (MAX_MT * TM)   // 9216 padded rows

typedef short short8 __attribute__((ext_vector_type(8)));
typedef float floatx4 __attribute__((ext_vector_type(4)));

__device__ __forceinline__ unsigned short f2bf(float f) {
  unsigned u = __float_as_uint(f);
  return (unsigned short)((u + 0x8000u) >> 16);
}

__device__ __forceinline__ void cvt_store8(unsigned short* dst, float4 a, float4 b) {
  short8 v;
  v[0] = (short)f2bf(a.x); v[1] = (short)f2bf(a.y);
  v[2] = (short)f2bf(a.z); v[3] = (short)f2bf(a.w);
  v[4] = (short)f2bf(b.x); v[5] = (short)f2bf(b.y);
  v[6] = (short)f2bf(b.z); v[7] = (short)f2bf(b.w);
  *(short8*)dst = v;
}

// async global->LDS, 16B per lane; lds dest = wave-uniform base + lane*16
__device__ __forceinline__ void gload_lds16(const unsigned short* g, unsigned short* l) {
  __builtin_amdgcn_global_load_lds(
      (const __attribute__((address_space(1))) unsigned int*)g,
      (__attribute__((address_space(3))) unsigned int*)l, 16, 0, 0);
}

// ---------------------------------------------------------------------------
// fp32 -> bf16 bulk convert (8 elements/thread, grid-stride)
// ---------------------------------------------------------------------------
__global__ void cvt_kernel(const float* __restrict__ src, unsigned short* __restrict__ dst,
                           int n8) {
  for (int i = blockIdx.x * blockDim.x + threadIdx.x; i < n8; i += gridDim.x * blockDim.x) {
    float4 a = ((const float4*)src)[2 * i];
    float4 b = ((const float4*)src)[2 * i + 1];
    cvt_store8(dst + (size_t)i * 8, a, b);
  }
}

// ---------------------------------------------------------------------------
// bucket tokens by expert into padded TM-row regions
// ---------------------------------------------------------------------------
__global__ void bucket_kernel(const int* __restrict__ ids, const float* __restrict__ tw,
                              int* __restrict__ hdr, int* __restrict__ tok,
                              float* __restrict__ wt) {
  __shared__ int cnt[EE];
  __shared__ int cur[EE];
  int tid = threadIdx.x;
  if (tid < EE) cnt[tid] = 0;
  __syncthreads();
  for (int p = tid; p < TKN; p += 256) atomicAdd(&cnt[ids[p]], 1);
  for (int r = tid; r < ROWS_PAD; r += 256) { tok[r] = 0; wt[r] = 0.f; }
  __syncthreads();
  if (tid == 0) {
    int rb = 0, tb = 0;
    for (int e = 0; e < EE; e++) {
      cur[e] = rb;
      int nt = (cnt[e] + TM - 1) / TM;
      for (int j = 0; j < nt; j++) hdr[1 + tb + j] = e;
      rb += nt * TM;
      tb += nt;
    }
    for (int m = tb; m < MAX_MT; m++) hdr[1 + m] = 0;
    hdr[0] = tb;
  }
  __syncthreads();
  for (int p = tid; p < TKN; p += 256) {
    int e = ids[p];
    int slot = atomicAdd(&cur[e], 1);
    tok[slot] = p / KK;
    wt[slot] = tw[p];
  }
}

// ---------------------------------------------------------------------------
// GEMM1: act[row, i] = silu(x_row.w_gate[e,i]) * (x_row.w_up[e,i])  (all bf16 in)
// 128x128 MFMA tile: 128 A rows (tokens) x (64 gate + 64 up) weight rows.
// ---------------------------------------------------------------------------
__global__ __launch_bounds__(256, 2)
void gemm1_kernel(const unsigned short* __restrict__ xb, const unsigned short* __restrict__ w13b,
                  const int* __restrict__ hdr, const int* __restrict__ tok,
                  unsigned short* __restrict__ act) {
  const int mt = blockIdx.x;
  if (mt >= hdr[0]) return;
  const int e = hdr[1 + mt];
  const int bn = blockIdx.y;          // act cols [bn*64, bn*64+64)
  const int row_base = mt * TM;
  const int tid = threadIdx.x;
  const int lane = tid & 63;
  const int wave = tid >> 6;

  __shared__ __align__(16) unsigned short As[TM][BK];
  __shared__ __align__(16) unsigned short Bs[TM][BK];

  // staging pointers: wave w, issue j covers LDS rows w*32+j*8 .. +8
  const int kcol = (lane & 7) * 8;        // element offset in K
  const unsigned short* gA[4];
  const unsigned short* gB[4];
  unsigned short* lA[4];
  unsigned short* lB[4];
#pragma unroll
  for (int j = 0; j < 4; j++) {
    int r = wave * 32 + j * 8 + (lane >> 3);
    gA[j] = xb + (size_t)tok[row_base + r] * HH + kcol;
    int wrow = (r < 64) ? (bn * 64 + r) : (CI + bn * 64 + (r - 64));
    gB[j] = w13b + ((size_t)e * (2 * CI) + wrow) * HH + kcol;
    lA[j] = &As[wave * 32 + j * 8][0];   // wave-uniform
    lB[j] = &Bs[wave * 32 + j * 8][0];
  }

  floatx4 acc[2][8];
#pragma unroll
  for (int mi = 0; mi < 2; mi++)
#pragma unroll
    for (int ni = 0; ni < 8; ni++) acc[mi][ni] = (floatx4){0.f, 0.f, 0.f, 0.f};

  const int lrow = lane & 15;
  const int quad = lane >> 4;
  const int m0 = wave * 32;

  for (int k0 = 0; k0 < HH; k0 += BK) {
    __syncthreads();
#pragma unroll
    for (int j = 0; j < 4; j++) {
      gload_lds16(gA[j] + k0, lA[j]);
      gload_lds16(gB[j] + k0, lB[j]);
    }
    __syncthreads();
#pragma unroll
    for (int kh = 0; kh < 2; kh++) {
      short8 af0 = *(const short8*)&As[m0 + lrow][kh * 32 + quad * 8];
      short8 af1 = *(const short8*)&As[m0 + 16 + lrow][kh * 32 + quad * 8];
#pragma unroll
      for (int ni = 0; ni < 8; ni++) {
        short8 bf = *(const short8*)&Bs[ni * 16 + lrow][kh * 32 + quad * 8];
        acc[0][ni] = __builtin_amdgcn_mfma_f32_16x16x32_bf16(af0, bf, acc[0][ni], 0, 0, 0);
        acc[1][ni] = __builtin_amdgcn_mfma_f32_16x16x32_bf16(af1, bf, acc[1][ni], 0, 0, 0);
      }
    }
  }

  const int col0 = bn * 64;
#pragma unroll
  for (int mi = 0; mi < 2; mi++) {
#pragma unroll
    for (int ni = 0; ni < 4; ni++) {
#pragma unroll
      for (int r = 0; r < 4; r++) {
        float g = acc[mi][ni][r];
        float uu = acc[mi][ni + 4][r];
        float s = g / (1.f + __expf(-g));
        int row = row_base + m0 + mi * 16 + quad * 4 + r;
        int col = col0 + ni * 16 + lrow;
        act[(size_t)row * CI + col] = f2bf(s * uu);
      }
    }
  }
}

// ---------------------------------------------------------------------------
// GEMM2: y[row,h] = act_row . w2[e,h,:]; out[tok[row],h] += wt[row]*y
// ---------------------------------------------------------------------------
__global__ __launch_bounds__(256, 2)
void gemm2_kernel(const unsigned short* __restrict__ act, const unsigned short* __restrict__ w2b,
                  const int* __restrict__ hdr, const int* __restrict__ tok,
                  const float* __restrict__ wt, float* __restrict__ out) {
  const int mt = blockIdx.x;
  if (mt >= hdr[0]) return;
  const int e = hdr[1 + mt];
  const int h0 = blockIdx.y * TM;
  const int row_base = mt * TM;
  const int tid = threadIdx.x;
  const int lane = tid & 63;
  const int wave = tid >> 6;

  __shared__ __align__(16) unsigned short As[TM][BK];
  __shared__ __align__(16) unsigned short Bs[TM][BK];
  __shared__ int tok_s[TM];
  __shared__ float wt_s[TM];

  if (tid < TM) {
    tok_s[tid] = tok[row_base + tid];
    wt_s[tid] = wt[row_base + tid];
  }

  const int kcol = (lane & 7) * 8;
  const unsigned short* gA[4];
  const unsigned short* gB[4];
  unsigned short* lA[4];
  unsigned short* lB[4];
#pragma unroll
  for (int j = 0; j < 4; j++) {
    int r = wave * 32 + j * 8 + (lane >> 3);
    gA[j] = act + (size_t)(row_base + r) * CI + kcol;
    gB[j] = w2b + ((size_t)e * HH + h0 + r) * CI + kcol;
    lA[j] = &As[wave * 32 + j * 8][0];
    lB[j] = &Bs[wave * 32 + j * 8][0];
  }

  floatx4 acc[2][8];
#pragma unroll
  for (int mi = 0; mi < 2; mi++)
#pragma unroll
    for (int ni = 0; ni < 8; ni++) acc[mi][ni] = (floatx4){0.f, 0.f, 0.f, 0.f};

  const int lrow = lane & 15;
  const int quad = lane >> 4;
  const int m0 = wave * 32;

  for (int k0 = 0; k0 < CI; k0 += BK) {
    __syncthreads();
#pragma unroll
    for (int j = 0; j < 4; j++) {
      gload_lds16(gA[j] + k0, lA[j]);
      gload_lds16(gB[j] + k0, lB[j]);
    }
    __syncthreads();
#pragma unroll
    for (int kh = 0; kh < 2; kh++) {
      short8 af0 = *(const short8*)&As[m0 + lrow][kh * 32 + quad * 8];
      short8 af1 = *(const short8*)&As[m0 + 16 + lrow][kh * 32 + quad * 8];
#pragma unroll
      for (int ni = 0; ni < 8; ni++) {
        short8 bf = *(const short8*)&Bs[ni * 16 + lrow][kh * 32 + quad * 8];
        acc[0][ni] = __builtin_amdgcn_mfma_f32_16x16x32_bf16(af0, bf, acc[0][ni], 0, 0, 0);
        acc[1][ni] = __builtin_amdgcn_mfma_f32_16x16x32_bf16(af1, bf, acc[1][ni], 0, 0, 0);
      }
    }
  }

#pragma unroll
  for (int mi = 0; mi < 2; mi++) {
#pragma unroll
    for (int ni = 0; ni < 8; ni++) {
#pragma unroll
      for (int r = 0; r < 4; r++) {
        int lr = m0 + mi * 16 + quad * 4 + r;
        float w = wt_s[lr];
        if (w != 0.f) {
          atomicAdd(out + (size_t)tok_s[lr] * HH + h0 + ni * 16 + lrow, acc[mi][ni][r] * w);
        }
      }
    }
  }
}

extern "C" void kernel_launch(void* const* d_in, const int* in_sizes, int n_in,
                              void* d_out, int out_size, void* d_ws, size_t ws_size,
                              hipStream_t stream) {
  const float* x   = (const float*)d_in[0];
  const float* w13 = (const float*)d_in[1];
  const float* w2  = (const float*)d_in[2];
  const float* tw  = (const float*)d_in[3];
  const int*   ids = (const int*)d_in[4];
  float* out = (float*)d_out;

  // workspace layout (bytes)
  char* ws = (char*)d_ws;
  int* hdr = (int*)ws;                                      // 512 B
  int* tok = (int*)(ws + 512);                              // 36864 B
  float* wt = (float*)(ws + 512 + ROWS_PAD * 4);            // 36864 B
  unsigned short* act  = (unsigned short*)(ws + 74240);                       // 51,904,512 B
  unsigned short* xb   = (unsigned short*)(ws + 74240 + 51904512ull);         // 16,777,216 B
  unsigned short* w13b = (unsigned short*)(ws + 74240 + 51904512ull + 16777216ull);   // 184,549,376 B
  unsigned short* w2b  = (unsigned short*)(ws + 74240 + 51904512ull + 16777216ull + 184549376ull); // 92,274,688

  hipMemsetAsync(d_out, 0, (size_t)out_size * sizeof(float), stream);
  bucket_kernel<<<1, 256, 0, stream>>>(ids, tw, hdr, tok, wt);
  cvt_kernel<<<2048, 256, 0, stream>>>(x, xb, TT * HH / 8);
  cvt_kernel<<<4096, 256, 0, stream>>>(w13, w13b, EE * 2 * CI * HH / 8);
  cvt_kernel<<<4096, 256, 0, stream>>>(w2, w2b, EE * HH * CI / 8);
  gemm1_kernel<<<dim3(MAX_MT, CI / 64), 256, 0, stream>>>(xb, w13b, hdr, tok, act);
  gemm2_kernel<<<dim3(MAX_MT, HH / TM), 256, 0, stream>>>(act, w2b, hdr, tok, wt, out);
}